// Round 7
// baseline (395.602 us; speedup 1.0000x reference)
//
#include <hip/hip_runtime.h>

// ---------------------------------------------------------------------------
// GSNet forward, live subgraph only (hk branch dead in reference).
// B=4, N=50000, T=12, HID=32, C=64, R=64.
// Round-7: k_out num+den via MFMA (bf16 hi/lo split, 3 terms, fp32-grade).
// qp/kvF/ksF stored packed u32 (bf16hi|bf16lo). D-layout -> LDS -> lane=node
// epilogue. k_node grid 2048.
// ---------------------------------------------------------------------------

#define NN    50000
#define EPSP  1e-4f
#define NRM   0.42044820762685725f   // 32^-0.25
#define HNRM2 0.08838834764831843f   // 0.5 * 32^-0.5

#define DEV __device__ __forceinline__

typedef __attribute__((ext_vector_type(8))) short bf16x8;
typedef __attribute__((ext_vector_type(4))) float f32x4;
#define MFMA16 __builtin_amdgcn_mfma_f32_16x16x32_bf16

DEV float bcast(float v, int lane) {
  return __int_as_float(__builtin_amdgcn_readlane(__float_as_int(v), lane));
}
template<int CTRL>
DEV float dpp_add(float x) {
  int p = __builtin_amdgcn_update_dpp(0, __float_as_int(x), CTRL, 0xF, 0xF, false);
  return x + __int_as_float(p);
}
template<int CTRL>
DEV float dpp_max(float x) {
  int p = __builtin_amdgcn_update_dpp(0, __float_as_int(x), CTRL, 0xF, 0xF, false);
  return fmaxf(x, __int_as_float(p));
}
DEV float wave_max(float x) {
  x = dpp_max<0xB1>(x); x = dpp_max<0x4E>(x);
  x = dpp_max<0x141>(x); x = dpp_max<0x140>(x);
  return fmaxf(fmaxf(bcast(x, 0), bcast(x, 16)),
               fmaxf(bcast(x, 32), bcast(x, 48)));
}

// pack f32 -> (bf16(x) << 16) | bf16(x - bf16(x)), both RNE
DEV unsigned packhl(float x) {
  unsigned u = __float_as_uint(x);
  unsigned hi = (u + 0x7fffu + ((u >> 16) & 1u)) >> 16;
  float lo = x - __uint_as_float(hi << 16);
  unsigned ul = __float_as_uint(lo);
  unsigned lb = (ul + 0x7fffu + ((ul >> 16) & 1u)) >> 16;
  return (hi << 16) | lb;
}

DEV void unpack8(uint4 a, uint4 b, bf16x8& h, bf16x8& l) {
  unsigned v[8] = {a.x, a.y, a.z, a.w, b.x, b.y, b.z, b.w};
  #pragma unroll
  for (int j = 0; j < 8; ++j) {
    h[j] = (short)(v[j] >> 16);
    l[j] = (short)(v[j] & 0xffffu);
  }
}

// ---------------------------------------------------------------------------
// k_weff: Weff[c][t] = fcA[c]@W_in[:,t];  beff[c] = fcA@b_in + fc_b
// ---------------------------------------------------------------------------
__global__ void k_weff(const float* __restrict__ fc_w,
                       const float* __restrict__ w_input,
                       const float* __restrict__ b_input,
                       const float* __restrict__ fc_b,
                       float* __restrict__ Weff, float* __restrict__ beff)
{
  const int c = threadIdx.x;  // 64 threads
  float fr[32];
  #pragma unroll
  for (int d = 0; d < 32; ++d) fr[d] = fc_w[c * 64 + d];
  #pragma unroll
  for (int t = 0; t < 12; ++t) {
    float s = 0.f;
    #pragma unroll
    for (int d = 0; d < 32; ++d) s = fmaf(fr[d], w_input[d * 12 + t], s);
    Weff[c * 12 + t] = s;
  }
  float s = fc_b[c];
  #pragma unroll
  for (int d = 0; d < 32; ++d) s = fmaf(fr[d], b_input[d], s);
  beff[c] = s;
}

// ---------------------------------------------------------------------------
// k_xpack: xp[i] = x[i*3] ; one float4 out per thread
// ---------------------------------------------------------------------------
__global__ __launch_bounds__(256) void k_xpack(const float* __restrict__ x,
                                               float* __restrict__ xp)
{
  const int i4 = blockIdx.x * 256 + threadIdx.x;
  if (i4 >= 600000) return;
  const float4* src = (const float4*)(x + (size_t)i4 * 12);
  float4 a = src[0], b = src[1], c = src[2];
  float4 o; o.x = a.x; o.y = a.w; o.z = b.z; o.w = c.y;  // elems 0,3,6,9
  ((float4*)xp)[i4] = o;
}

// ---------------------------------------------------------------------------
// k_node (batch-independent): nv1/nv2 (split halves), g2, qphl(packed), ek;
// per-block partials ekspart[blk][64], mkpart[blk].
// ---------------------------------------------------------------------------
__global__ __launch_bounds__(256) void k_node(
    const float* __restrict__ node_emb,
    const float* __restrict__ w1, const float* __restrict__ b1,
    const float* __restrict__ w2, const float* __restrict__ b2,
    const float* __restrict__ rm1, const float* __restrict__ fc_w,
    const float* __restrict__ beff,
    unsigned* __restrict__ qphl, float* __restrict__ ek_out,
    float* __restrict__ g2_out,
    float* __restrict__ ekspart, float* __restrict__ mkpart)
{
  const int lane = threadIdx.x & 63;
  const int wv = threadIdx.x >> 6;
  const int j = lane & 31;
  const int gw = (blockIdx.x * 256 + threadIdx.x) >> 6;
  const int nw = (gridDim.x * 256) >> 6;

  __shared__ float nvs[4][68];
  __shared__ float eks_s[4][64];
  __shared__ float mk_s[4];

  float wrow[32], fbr[32], rmr[32];
  const float* wsel = (lane < 32) ? w1 : w2;
  #pragma unroll
  for (int d = 0; d < 32; ++d) {
    wrow[d] = wsel[j * 32 + d];
    fbr[d]  = fc_w[lane * 64 + 32 + d];
    rmr[d]  = rm1[lane * 32 + d];
  }
  const float bsel = (lane < 32) ? b1[j] : b2[j];
  const float be = beff[lane];

  float eks_acc = 0.f, mk_run = -3.0e38f;

  for (int n = gw; n < NN; n += nw) {
    const int nu = __builtin_amdgcn_readfirstlane(n);
    const float4* ne4 = (const float4*)(node_emb + (size_t)nu * 32);
    float nd0[32];
    #pragma unroll
    for (int k = 0; k < 8; ++k) {
      float4 c = ne4[k];
      nd0[4*k] = c.x; nd0[4*k+1] = c.y; nd0[4*k+2] = c.z; nd0[4*k+3] = c.w;
    }
    float a0 = bsel, a1 = 0.f, a2 = 0.f, a3 = 0.f;
    #pragma unroll
    for (int d = 0; d < 32; d += 4) {
      a0 = fmaf(nd0[d],   wrow[d],   a0);
      a1 = fmaf(nd0[d+1], wrow[d+1], a1);
      a2 = fmaf(nd0[d+2], wrow[d+2], a2);
      a3 = fmaf(nd0[d+3], wrow[d+3], a3);
    }
    const float nv = (a0 + a1) + (a2 + a3);
    float g0 = be, g1 = 0.f, g2a = 0.f, g3 = 0.f;
    #pragma unroll
    for (int d = 0; d < 32; d += 4) {
      g0 = fmaf(nd0[d],   fbr[d],   g0);
      g1 = fmaf(nd0[d+1], fbr[d+1], g1);
      g2a = fmaf(nd0[d+2], fbr[d+2], g2a);
      g3 = fmaf(nd0[d+3], fbr[d+3], g3);
    }
    g2_out[(size_t)nu * 64 + lane] = (g0 + g1) + (g2a + g3);
    float t = nv * nv;
    t = dpp_add<0xB1>(t); t = dpp_add<0x4E>(t);
    t = dpp_add<0x141>(t); t = dpp_add<0x140>(t);
    const float dq = bcast(t, 0) + bcast(t, 16);
    const float dk = bcast(t, 32) + bcast(t, 48);
    nvs[wv][lane] = nv;                    // same-wave RAW
    float q0 = 0.f, q1 = 0.f, k0 = 0.f, k1 = 0.f;
    const float4* nv1p = (const float4*)&nvs[wv][0];
    const float4* nv2p = (const float4*)&nvs[wv][32];
    #pragma unroll
    for (int k = 0; k < 8; ++k) {
      float4 c = nv1p[k];
      q0 = fmaf(c.x, rmr[4*k],   q0); q1 = fmaf(c.y, rmr[4*k+1], q1);
      q0 = fmaf(c.z, rmr[4*k+2], q0); q1 = fmaf(c.w, rmr[4*k+3], q1);
    }
    #pragma unroll
    for (int k = 0; k < 8; ++k) {
      float4 c = nv2p[k];
      k0 = fmaf(c.x, rmr[4*k],   k0); k1 = fmaf(c.y, rmr[4*k+1], k1);
      k0 = fmaf(c.z, rmr[4*k+2], k0); k1 = fmaf(c.w, rmr[4*k+3], k1);
    }
    const float ddq = (q0 + q1) * NRM;
    const float ddk = (k0 + k1) * NRM;
    const float mq = wave_max(ddq);
    const float qpv = __expf(ddq - HNRM2 * dq - mq) + EPSP;
    const float ekv = __expf(ddk - HNRM2 * dk);
    mk_run = fmaxf(mk_run, ddk);
    eks_acc += ekv;
    qphl[(size_t)nu * 64 + lane] = packhl(qpv);
    ek_out[(size_t)nu * 64 + lane] = ekv;
  }

  eks_s[wv][lane] = eks_acc;
  const float mw = wave_max(mk_run);
  if (lane == 0) mk_s[wv] = mw;
  __syncthreads();
  if (wv == 0) {
    ekspart[blockIdx.x * 64 + lane] =
        (eks_s[0][lane] + eks_s[1][lane]) + (eks_s[2][lane] + eks_s[3][lane]);
    if (lane == 0)
      mkpart[blockIdx.x] =
          fmaxf(fmaxf(mk_s[0], mk_s[1]), fmaxf(mk_s[2], mk_s[3]));
  }
}

// ---------------------------------------------------------------------------
// k_kv: v = relu(Weff@xt + g2[n]); partial E_kv/Vsum per block (no atomics)
// grid 1024: b = blk&3, kb = blk>>2 (256 partials per batch)
// ---------------------------------------------------------------------------
__global__ __launch_bounds__(256) void k_kv(
    const float* __restrict__ xp, const float* __restrict__ Weff,
    const float* __restrict__ g2_in, const float* __restrict__ ek_in,
    float* __restrict__ part, float* __restrict__ vpart)
{
  const int lane = threadIdx.x & 63;
  const int wv = threadIdx.x >> 6;
  const int b = blockIdx.x & 3;
  const int kb = blockIdx.x >> 2;
  const int wInB = kb * 4 + wv;
  const int strideB = 1024;

  float wrow[12];
  #pragma unroll
  for (int t = 0; t < 12; ++t) wrow[t] = Weff[lane * 12 + t];

  float acc[64];
  #pragma unroll
  for (int r = 0; r < 64; ++r) acc[r] = 0.f;
  float vs = 0.f;

  for (int n = wInB; n < NN; n += strideB) {
    const int nu = __builtin_amdgcn_readfirstlane(n);
    const float4* xp4 = (const float4*)(xp + ((size_t)b * NN + nu) * 12);
    float4 c0 = xp4[0], c1 = xp4[1], c2 = xp4[2];
    float v0 = fmaf(c0.x, wrow[0], g2_in[(size_t)nu * 64 + lane]);
    float v1 = c0.y * wrow[1], v2 = c0.z * wrow[2], v3 = c0.w * wrow[3];
    v0 = fmaf(c1.x, wrow[4], v0); v1 = fmaf(c1.y, wrow[5], v1);
    v2 = fmaf(c1.z, wrow[6], v2); v3 = fmaf(c1.w, wrow[7], v3);
    v0 = fmaf(c2.x, wrow[8], v0); v1 = fmaf(c2.y, wrow[9], v1);
    v2 = fmaf(c2.z, wrow[10], v2); v3 = fmaf(c2.w, wrow[11], v3);
    const float v = fmaxf((v0 + v1) + (v2 + v3), 0.f);
    const float4* ekp = (const float4*)(ek_in + (size_t)nu * 64);
    #pragma unroll
    for (int k = 0; k < 16; ++k) {
      float4 e = ekp[k];
      acc[4*k]   = fmaf(e.x, v, acc[4*k]);
      acc[4*k+1] = fmaf(e.y, v, acc[4*k+1]);
      acc[4*k+2] = fmaf(e.z, v, acc[4*k+2]);
      acc[4*k+3] = fmaf(e.w, v, acc[4*k+3]);
    }
    vs += v;
  }

  __shared__ float pkv[64][65];
  __shared__ float pvs[64];
  if (wv == 0) {
    #pragma unroll
    for (int r = 0; r < 64; ++r) pkv[r][lane] = acc[r];
    pvs[lane] = vs;
  }
  __syncthreads();
  for (int w = 1; w < 4; ++w) {
    if (wv == w) {
      #pragma unroll
      for (int r = 0; r < 64; ++r) pkv[r][lane] += acc[r];
      pvs[lane] += vs;
    }
    __syncthreads();
  }
  const size_t base = (size_t)(b * 256 + kb) * 4096;
  for (int i = threadIdx.x; i < 4096; i += 256)
    part[base + i] = pkv[i >> 6][i & 63];
  if (threadIdx.x < 64)
    vpart[(b * 256 + kb) * 64 + threadIdx.x] = pvs[threadIdx.x];
}

// ---------------------------------------------------------------------------
// k_vred2: blocks 0-3: Vsum[b][c] = sum_kb vpart.
//   block 4: eks col-sums + global max -> sc = exp(-M); ks5frag (den B-tile,
//   ksF in col 0, packed hi|lo).
// ---------------------------------------------------------------------------
__global__ __launch_bounds__(256) void k_vred2(
    const float* __restrict__ vpart, const float* __restrict__ ekspart,
    const float* __restrict__ mkpart,
    float* __restrict__ Vsum, unsigned* __restrict__ ks5frag,
    float* __restrict__ sc_out)
{
  const int c = threadIdx.x & 63, grp = threadIdx.x >> 6;  // 4 groups
  if (blockIdx.x < 4) {
    const int b = blockIdx.x;
    float s = 0.f;
    for (int kb = grp; kb < 256; kb += 4)
      s += vpart[(size_t)(b * 256 + kb) * 64 + c];
    __shared__ float ls[4][64];
    ls[grp][c] = s;
    __syncthreads();
    if (grp == 0)
      Vsum[b * 64 + c] = (ls[0][c] + ls[1][c]) + (ls[2][c] + ls[3][c]);
  } else {
    // zero ks5frag (1024 u32) first
    #pragma unroll
    for (int q = 0; q < 4; ++q) ks5frag[threadIdx.x * 4 + q] = 0u;
    float s = 0.f;
    for (int kb = grp; kb < 2048; kb += 4)
      s += ekspart[(size_t)kb * 64 + c];
    float m = -3.0e38f;
    for (int i = threadIdx.x; i < 2048; i += 256) m = fmaxf(m, mkpart[i]);
    m = wave_max(m);
    __shared__ float ls2[4][64];
    __shared__ float ms[4];
    ls2[grp][c] = s;
    if (c == 0) ms[grp] = m;
    __syncthreads();
    if (grp == 0) {
      const float M = fmaxf(fmaxf(ms[0], ms[1]), fmaxf(ms[2], ms[3]));
      const float scv = __expf(-M);
      const float ksv = fmaf(scv,
          (ls2[0][c] + ls2[1][c]) + (ls2[2][c] + ls2[3][c]),
          EPSP * (float)NN);
      // B-frag position for element (k=r, col=0): lane=((r>>3)&3)*16, j=r&7
      const int r = c;
      ks5frag[(r >> 5) * 512 + ((r >> 3) & 3) * 128 + (r & 7)] = packhl(ksv);
      if (c == 0) *sc_out = scv;
    }
  }
}

// ---------------------------------------------------------------------------
// k_red: kv = sc*sum_kb part + eps*Vsum, written directly in MFMA B-frag
// layout, packed hi|lo. grid 512 x 256.
// ---------------------------------------------------------------------------
__global__ __launch_bounds__(256) void k_red(
    const float* __restrict__ part, const float* __restrict__ Vsum,
    const float* __restrict__ sc_in, unsigned* __restrict__ kvfrag)
{
  const int t = threadIdx.x;
  const int col0 = blockIdx.x * 32;
  const int c32 = t & 31, grp = t >> 5;          // 8 groups
  const int gid = col0 + c32;
  const int b = gid >> 12, idx = gid & 4095;
  float s = 0.f;
  for (int kb = grp; kb < 256; kb += 8)
    s += part[(size_t)(b * 256 + kb) * 4096 + idx];
  __shared__ float ls[8][33];
  ls[grp][c32] = s;
  __syncthreads();
  if (grp == 0) {
    float tot = 0.f;
    #pragma unroll
    for (int g = 0; g < 8; ++g) tot += ls[g][c32];
    const int r = idx >> 6, c = idx & 63;
    const float val = fmaf(*sc_in, tot, EPSP * Vsum[b * 64 + c]);
    // B-frag: tile ct=c>>4, ks=r>>5, lane=((r>>3)&3)*16+(c&15), j=r&7
    const int fi = (((b * 4 + (c >> 4)) * 2 + (r >> 5)) * 64 +
                    ((r >> 3) & 3) * 16 + (c & 15)) * 8 + (r & 7);
    kvfrag[fi] = packhl(val);
  }
}

// ---------------------------------------------------------------------------
// k_out: one wave per (batch, 64-node chunk). num+den via MFMA 16x16x32 bf16
// hi/lo (3 terms). D-layout -> LDS [64][65]+den[64] -> lane=node epilogue.
// ---------------------------------------------------------------------------
__global__ __launch_bounds__(64) void k_out(
    const float* __restrict__ xp, const float* __restrict__ node_emb,
    const float* __restrict__ w_input, const float* __restrict__ b_input,
    const unsigned* __restrict__ qphl, const unsigned* __restrict__ kvfrag,
    const unsigned* __restrict__ ks5frag,
    const float* __restrict__ ln_g, const float* __restrict__ ln_b,
    const float* __restrict__ w_reg, const float* __restrict__ b_reg,
    float* __restrict__ out)
{
  __shared__ float hb[64 * 65 + 64];
  const int lane = threadIdx.x;
  const int bu = __builtin_amdgcn_readfirstlane(blockIdx.x & 3);
  const int n0 = (blockIdx.x >> 2) * 64;
  const int arow = lane & 15, akg = lane >> 4;

  f32x4 acc[4][4];
  f32x4 acc5[4];
  #pragma unroll
  for (int nt = 0; nt < 4; ++nt) {
    #pragma unroll
    for (int ct = 0; ct < 4; ++ct) acc[nt][ct] = (f32x4)0.f;
    acc5[nt] = (f32x4)0.f;
  }

  #pragma unroll
  for (int ks = 0; ks < 2; ++ks) {
    // A frags: qp rows (node = n0+nt*16+arow, k = ks*32+akg*8+j)
    bf16x8 Ah[4], Al[4];
    #pragma unroll
    for (int nt = 0; nt < 4; ++nt) {
      const uint4* ap = (const uint4*)(qphl +
          (size_t)(n0 + nt * 16 + arow) * 64 + ks * 32 + akg * 8);
      unpack8(ap[0], ap[1], Ah[nt], Al[nt]);
    }
    // B frags per column-tile
    #pragma unroll
    for (int ct = 0; ct < 4; ++ct) {
      const uint4* bp = (const uint4*)(kvfrag +
          ((size_t)((bu * 4 + ct) * 2 + ks) * 64 + lane) * 8);
      bf16x8 Bh, Bl;
      unpack8(bp[0], bp[1], Bh, Bl);
      #pragma unroll
      for (int nt = 0; nt < 4; ++nt) {
        acc[nt][ct] = MFMA16(Ah[nt], Bh, acc[nt][ct], 0, 0, 0);
        acc[nt][ct] = MFMA16(Ah[nt], Bl, acc[nt][ct], 0, 0, 0);
        acc[nt][ct] = MFMA16(Al[nt], Bh, acc[nt][ct], 0, 0, 0);
      }
    }
    // den tile (ksF in col 0)
    {
      const uint4* kp = (const uint4*)(ks5frag + ((size_t)(ks * 64 + lane)) * 8);
      bf16x8 Kh, Kl;
      unpack8(kp[0], kp[1], Kh, Kl);
      #pragma unroll
      for (int nt = 0; nt < 4; ++nt) {
        acc5[nt] = MFMA16(Ah[nt], Kh, acc5[nt], 0, 0, 0);
        acc5[nt] = MFMA16(Ah[nt], Kl, acc5[nt], 0, 0, 0);
        acc5[nt] = MFMA16(Al[nt], Kh, acc5[nt], 0, 0, 0);
      }
    }
  }

  // dump D-layout -> LDS: row=nt*16+akg*4+reg, col=ct*16+arow
  #pragma unroll
  for (int nt = 0; nt < 4; ++nt)
    #pragma unroll
    for (int ct = 0; ct < 4; ++ct)
      #pragma unroll
      for (int reg = 0; reg < 4; ++reg)
        hb[(nt * 16 + akg * 4 + reg) * 65 + ct * 16 + arow] = acc[nt][ct][reg];
  if (arow == 0) {
    #pragma unroll
    for (int nt = 0; nt < 4; ++nt)
      #pragma unroll
      for (int reg = 0; reg < 4; ++reg)
        hb[4160 + nt * 16 + akg * 4 + reg] = acc5[nt][reg];
  }
  __syncthreads();

  // ---- per-lane epilogue: lane = node ----
  const int n = n0 + lane;
  const bool act = (n < NN);
  const int nld = act ? n : (NN - 1);
  const float den = hb[4160 + lane];
  const float rden = 1.f / den;

  float o_[12];
  #pragma unroll
  for (int o = 0; o < 12; ++o) o_[o] = b_reg[o];
  float h[64];

  {
    const float4* xp4 = (const float4*)(xp + ((size_t)bu * NN + nld) * 12);
    const float4 X0 = xp4[0], X1 = xp4[1], X2 = xp4[2];
    #pragma unroll
    for (int c = 0; c < 32; ++c) {
      float a = fmaf(X0.x, w_input[c*12+0], b_input[c]);
      a = fmaf(X0.y, w_input[c*12+1],  a);
      a = fmaf(X0.z, w_input[c*12+2],  a);
      a = fmaf(X0.w, w_input[c*12+3],  a);
      a = fmaf(X1.x, w_input[c*12+4],  a);
      a = fmaf(X1.y, w_input[c*12+5],  a);
      a = fmaf(X1.z, w_input[c*12+6],  a);
      a = fmaf(X1.w, w_input[c*12+7],  a);
      a = fmaf(X2.x, w_input[c*12+8],  a);
      a = fmaf(X2.y, w_input[c*12+9],  a);
      a = fmaf(X2.z, w_input[c*12+10], a);
      a = fmaf(X2.w, w_input[c*12+11], a);
      const float rx = fmaxf(a, 0.f);
      #pragma unroll
      for (int o = 0; o < 12; ++o) o_[o] = fmaf(rx, w_reg[o*128 + c], o_[o]);
      h[c] = fmaf(hb[lane * 65 + c], rden, a);
    }
    const float4* ne4 = (const float4*)(node_emb + (size_t)nld * 32);
    #pragma unroll
    for (int k = 0; k < 8; ++k) {
      const float4 nv = ne4[k];
      const float e[4] = {nv.x, nv.y, nv.z, nv.w};
      #pragma unroll
      for (int jj = 0; jj < 4; ++jj) {
        const int c = 32 + 4*k + jj;
        const float rx = fmaxf(e[jj], 0.f);
        #pragma unroll
        for (int o = 0; o < 12; ++o) o_[o] = fmaf(rx, w_reg[o*128 + c], o_[o]);
        h[c] = fmaf(hb[lane * 65 + c], rden, e[jj]);
      }
    }
  }

  // LN over 64 channels (per-lane serial)
  float t0 = 0.f, t1 = 0.f, t2 = 0.f, t3 = 0.f;
  #pragma unroll
  for (int c = 0; c < 64; c += 4) {
    t0 += h[c]; t1 += h[c+1]; t2 += h[c+2]; t3 += h[c+3];
  }
  const float mean = ((t0 + t1) + (t2 + t3)) * 0.015625f;
  t0 = t1 = t2 = t3 = 0.f;
  #pragma unroll
  for (int c = 0; c < 64; c += 4) {
    const float d0 = h[c] - mean, d1 = h[c+1] - mean;
    const float d2 = h[c+2] - mean, d3 = h[c+3] - mean;
    t0 = fmaf(d0, d0, t0); t1 = fmaf(d1, d1, t1);
    t2 = fmaf(d2, d2, t2); t3 = fmaf(d3, d3, t3);
  }
  const float rstd = rsqrtf(((t0 + t1) + (t2 + t3)) * 0.015625f + 1e-5f);
  #pragma unroll
  for (int c = 0; c < 64; ++c)
    h[c] = fmaxf(fmaf((h[c] - mean) * rstd, ln_g[c], ln_b[c]), 0.f);

  #pragma unroll 2
  for (int o = 0; o < 12; ++o) {
    float a0 = o_[o], a1 = 0.f, a2 = 0.f, a3 = 0.f;
    #pragma unroll
    for (int c = 0; c < 64; c += 4) {
      a0 = fmaf(h[c],   w_reg[o*128 + 64 + c], a0);
      a1 = fmaf(h[c+1], w_reg[o*128 + 65 + c], a1);
      a2 = fmaf(h[c+2], w_reg[o*128 + 66 + c], a2);
      a3 = fmaf(h[c+3], w_reg[o*128 + 67 + c], a3);
    }
    o_[o] = (a0 + a1) + (a2 + a3);
  }

  if (act) {
    float* ob = out + ((size_t)bu * NN + n) * 12;
    float4 s0, s1, s2;
    s0.x = o_[0];  s0.y = o_[1];  s0.z = o_[2];  s0.w = o_[3];
    s1.x = o_[4];  s1.y = o_[5];  s1.z = o_[6];  s1.w = o_[7];
    s2.x = o_[8];  s2.y = o_[9];  s2.z = o_[10]; s2.w = o_[11];
    ((float4*)ob)[0] = s0; ((float4*)ob)[1] = s1; ((float4*)ob)[2] = s2;
  }
}

// ---------------------------------------------------------------------------
extern "C" void kernel_launch(void* const* d_in, const int* in_sizes, int n_in,
                              void* d_out, int out_size, void* d_ws, size_t ws_size,
                              hipStream_t stream) {
  (void)in_sizes; (void)n_in; (void)out_size; (void)ws_size;
  const float* x       = (const float*)d_in[0];
  const float* node    = (const float*)d_in[1];
  const float* w_input = (const float*)d_in[4];
  const float* b_input = (const float*)d_in[5];
  const float* w1      = (const float*)d_in[6];
  const float* b1      = (const float*)d_in[7];
  const float* w2      = (const float*)d_in[8];
  const float* b2      = (const float*)d_in[9];
  const float* fc_w    = (const float*)d_in[14];
  const float* fc_b    = (const float*)d_in[15];
  const float* ln_g    = (const float*)d_in[18];
  const float* ln_b    = (const float*)d_in[19];
  const float* w_reg   = (const float*)d_in[22];
  const float* b_reg   = (const float*)d_in[23];
  const float* rm1     = (const float*)d_in[24];

  // workspace layout (float offsets):
  float* ws         = (float*)d_ws;
  float* sc         = ws;                    // 1 (pad to 64)
  float* Weff       = ws + 64;               // 768
  float* beff       = ws + 832;              // 64
  unsigned* kvfrag  = (unsigned*)(ws + 896);    // 16384
  unsigned* ks5frag = (unsigned*)(ws + 17280);  // 1024
  float* Vsum       = ws + 18304;            // 256
  float* mkpart     = ws + 18560;            // 2048
  float* ekspart    = ws + 20608;            // 2048*64 = 131072
  unsigned* qphl    = (unsigned*)(ws + 151680); // 3,200,000
  float* ek         = ws + 3351680;          // 3,200,000
  float* g2         = ws + 6551680;          // 3,200,000
  float* xp         = ws + 9751680;          // 2,400,000
  float* part       = ws + 12151680;         // 1024*4096 = 4,194,304
  float* vpart      = ws + 16345984;         // 1024*64 = 65,536
  // total 16,411,520 floats = 65.6 MB (R4's 69.4 MB passed -> fits)

  k_weff<<<1, 64, 0, stream>>>(fc_w, w_input, b_input, fc_b, Weff, beff);
  k_xpack<<<2344, 256, 0, stream>>>(x, xp);
  k_node<<<2048, 256, 0, stream>>>(node, w1, b1, w2, b2, rm1, fc_w, beff,
                                   qphl, ek, g2, ekspart, mkpart);
  k_kv<<<1024, 256, 0, stream>>>(xp, Weff, g2, ek, part, vpart);
  k_vred2<<<5, 256, 0, stream>>>(vpart, ekspart, mkpart, Vsum, ks5frag, sc);
  k_red<<<512, 256, 0, stream>>>(part, Vsum, sc, kvfrag);
  k_out<<<3128, 64, 0, stream>>>(xp, node, w_input, b_input, qphl, kvfrag,
                                 ks5frag, ln_g, ln_b, w_reg, b_reg,
                                 (float*)d_out);
}

// Round 8
// 275.036 us; speedup vs baseline: 1.4384x; 1.4384x over previous
//
#include <hip/hip_runtime.h>

// ---------------------------------------------------------------------------
// GSNet forward, live subgraph only (hk branch dead in reference).
// B=4, N=50000, T=12, HID=32, C=64, R=64.
// Round-8: reduction tail fixed. R7's k_vred2 was a 512-iteration serial
// load-latency chain (124us, VALUBusy 0.02%). Now: partials written
// TRANSPOSED (ekspartT[c][2048], vpartT[(b,c)][256]) -> k_fin1 does wave-per-
// output coalesced float4 reductions; k_fin2 builds ks5frag. k_out stays MFMA.
// ---------------------------------------------------------------------------

#define NN    50000
#define EPSP  1e-4f
#define NRM   0.42044820762685725f   // 32^-0.25
#define HNRM2 0.08838834764831843f   // 0.5 * 32^-0.5

#define DEV __device__ __forceinline__

typedef __attribute__((ext_vector_type(8))) short bf16x8;
typedef __attribute__((ext_vector_type(4))) float f32x4;
#define MFMA16 __builtin_amdgcn_mfma_f32_16x16x32_bf16

DEV float bcast(float v, int lane) {
  return __int_as_float(__builtin_amdgcn_readlane(__float_as_int(v), lane));
}
template<int CTRL>
DEV float dpp_add(float x) {
  int p = __builtin_amdgcn_update_dpp(0, __float_as_int(x), CTRL, 0xF, 0xF, false);
  return x + __int_as_float(p);
}
template<int CTRL>
DEV float dpp_max(float x) {
  int p = __builtin_amdgcn_update_dpp(0, __float_as_int(x), CTRL, 0xF, 0xF, false);
  return fmaxf(x, __int_as_float(p));
}
DEV float wave_sum(float x) {
  x = dpp_add<0xB1>(x); x = dpp_add<0x4E>(x);
  x = dpp_add<0x141>(x); x = dpp_add<0x140>(x);
  return (bcast(x, 0) + bcast(x, 16)) + (bcast(x, 32) + bcast(x, 48));
}
DEV float wave_max(float x) {
  x = dpp_max<0xB1>(x); x = dpp_max<0x4E>(x);
  x = dpp_max<0x141>(x); x = dpp_max<0x140>(x);
  return fmaxf(fmaxf(bcast(x, 0), bcast(x, 16)),
               fmaxf(bcast(x, 32), bcast(x, 48)));
}

// pack f32 -> (bf16(x) << 16) | bf16(x - bf16(x)), both RNE
DEV unsigned packhl(float x) {
  unsigned u = __float_as_uint(x);
  unsigned hi = (u + 0x7fffu + ((u >> 16) & 1u)) >> 16;
  float lo = x - __uint_as_float(hi << 16);
  unsigned ul = __float_as_uint(lo);
  unsigned lb = (ul + 0x7fffu + ((ul >> 16) & 1u)) >> 16;
  return (hi << 16) | lb;
}

DEV void unpack8(uint4 a, uint4 b, bf16x8& h, bf16x8& l) {
  unsigned v[8] = {a.x, a.y, a.z, a.w, b.x, b.y, b.z, b.w};
  #pragma unroll
  for (int j = 0; j < 8; ++j) {
    h[j] = (short)(v[j] >> 16);
    l[j] = (short)(v[j] & 0xffffu);
  }
}

// ---------------------------------------------------------------------------
// k_weff: Weff[c][t] = fcA[c]@W_in[:,t];  beff[c] = fcA@b_in + fc_b
// ---------------------------------------------------------------------------
__global__ void k_weff(const float* __restrict__ fc_w,
                       const float* __restrict__ w_input,
                       const float* __restrict__ b_input,
                       const float* __restrict__ fc_b,
                       float* __restrict__ Weff, float* __restrict__ beff)
{
  const int c = threadIdx.x;  // 64 threads
  float fr[32];
  #pragma unroll
  for (int d = 0; d < 32; ++d) fr[d] = fc_w[c * 64 + d];
  #pragma unroll
  for (int t = 0; t < 12; ++t) {
    float s = 0.f;
    #pragma unroll
    for (int d = 0; d < 32; ++d) s = fmaf(fr[d], w_input[d * 12 + t], s);
    Weff[c * 12 + t] = s;
  }
  float s = fc_b[c];
  #pragma unroll
  for (int d = 0; d < 32; ++d) s = fmaf(fr[d], b_input[d], s);
  beff[c] = s;
}

// ---------------------------------------------------------------------------
// k_xpack: xp[i] = x[i*3] ; one float4 out per thread
// ---------------------------------------------------------------------------
__global__ __launch_bounds__(256) void k_xpack(const float* __restrict__ x,
                                               float* __restrict__ xp)
{
  const int i4 = blockIdx.x * 256 + threadIdx.x;
  if (i4 >= 600000) return;
  const float4* src = (const float4*)(x + (size_t)i4 * 12);
  float4 a = src[0], b = src[1], c = src[2];
  float4 o; o.x = a.x; o.y = a.w; o.z = b.z; o.w = c.y;  // elems 0,3,6,9
  ((float4*)xp)[i4] = o;
}

// ---------------------------------------------------------------------------
// k_node (batch-independent): nv1/nv2 (split halves), g2, qphl(packed), ek;
// per-block partials ekspartT[c][2048] (scatter), mkpart[blk].
// ---------------------------------------------------------------------------
__global__ __launch_bounds__(256) void k_node(
    const float* __restrict__ node_emb,
    const float* __restrict__ w1, const float* __restrict__ b1,
    const float* __restrict__ w2, const float* __restrict__ b2,
    const float* __restrict__ rm1, const float* __restrict__ fc_w,
    const float* __restrict__ beff,
    unsigned* __restrict__ qphl, float* __restrict__ ek_out,
    float* __restrict__ g2_out,
    float* __restrict__ ekspartT, float* __restrict__ mkpart)
{
  const int lane = threadIdx.x & 63;
  const int wv = threadIdx.x >> 6;
  const int j = lane & 31;
  const int gw = (blockIdx.x * 256 + threadIdx.x) >> 6;
  const int nw = (gridDim.x * 256) >> 6;

  __shared__ float nvs[4][68];
  __shared__ float eks_s[4][64];
  __shared__ float mk_s[4];

  float wrow[32], fbr[32], rmr[32];
  const float* wsel = (lane < 32) ? w1 : w2;
  #pragma unroll
  for (int d = 0; d < 32; ++d) {
    wrow[d] = wsel[j * 32 + d];
    fbr[d]  = fc_w[lane * 64 + 32 + d];
    rmr[d]  = rm1[lane * 32 + d];
  }
  const float bsel = (lane < 32) ? b1[j] : b2[j];
  const float be = beff[lane];

  float eks_acc = 0.f, mk_run = -3.0e38f;

  for (int n = gw; n < NN; n += nw) {
    const int nu = __builtin_amdgcn_readfirstlane(n);
    const float4* ne4 = (const float4*)(node_emb + (size_t)nu * 32);
    float nd0[32];
    #pragma unroll
    for (int k = 0; k < 8; ++k) {
      float4 c = ne4[k];
      nd0[4*k] = c.x; nd0[4*k+1] = c.y; nd0[4*k+2] = c.z; nd0[4*k+3] = c.w;
    }
    float a0 = bsel, a1 = 0.f, a2 = 0.f, a3 = 0.f;
    #pragma unroll
    for (int d = 0; d < 32; d += 4) {
      a0 = fmaf(nd0[d],   wrow[d],   a0);
      a1 = fmaf(nd0[d+1], wrow[d+1], a1);
      a2 = fmaf(nd0[d+2], wrow[d+2], a2);
      a3 = fmaf(nd0[d+3], wrow[d+3], a3);
    }
    const float nv = (a0 + a1) + (a2 + a3);
    float g0 = be, g1 = 0.f, g2a = 0.f, g3 = 0.f;
    #pragma unroll
    for (int d = 0; d < 32; d += 4) {
      g0 = fmaf(nd0[d],   fbr[d],   g0);
      g1 = fmaf(nd0[d+1], fbr[d+1], g1);
      g2a = fmaf(nd0[d+2], fbr[d+2], g2a);
      g3 = fmaf(nd0[d+3], fbr[d+3], g3);
    }
    g2_out[(size_t)nu * 64 + lane] = (g0 + g1) + (g2a + g3);
    float t = nv * nv;
    t = dpp_add<0xB1>(t); t = dpp_add<0x4E>(t);
    t = dpp_add<0x141>(t); t = dpp_add<0x140>(t);
    const float dq = bcast(t, 0) + bcast(t, 16);
    const float dk = bcast(t, 32) + bcast(t, 48);
    nvs[wv][lane] = nv;                    // same-wave RAW
    float q0 = 0.f, q1 = 0.f, k0 = 0.f, k1 = 0.f;
    const float4* nv1p = (const float4*)&nvs[wv][0];
    const float4* nv2p = (const float4*)&nvs[wv][32];
    #pragma unroll
    for (int k = 0; k < 8; ++k) {
      float4 c = nv1p[k];
      q0 = fmaf(c.x, rmr[4*k],   q0); q1 = fmaf(c.y, rmr[4*k+1], q1);
      q0 = fmaf(c.z, rmr[4*k+2], q0); q1 = fmaf(c.w, rmr[4*k+3], q1);
    }
    #pragma unroll
    for (int k = 0; k < 8; ++k) {
      float4 c = nv2p[k];
      k0 = fmaf(c.x, rmr[4*k],   k0); k1 = fmaf(c.y, rmr[4*k+1], k1);
      k0 = fmaf(c.z, rmr[4*k+2], k0); k1 = fmaf(c.w, rmr[4*k+3], k1);
    }
    const float ddq = (q0 + q1) * NRM;
    const float ddk = (k0 + k1) * NRM;
    const float mq = wave_max(ddq);
    const float qpv = __expf(ddq - HNRM2 * dq - mq) + EPSP;
    const float ekv = __expf(ddk - HNRM2 * dk);
    mk_run = fmaxf(mk_run, ddk);
    eks_acc += ekv;
    qphl[(size_t)nu * 64 + lane] = packhl(qpv);
    ek_out[(size_t)nu * 64 + lane] = ekv;
  }

  eks_s[wv][lane] = eks_acc;
  const float mw = wave_max(mk_run);
  if (lane == 0) mk_s[wv] = mw;
  __syncthreads();
  if (wv == 0) {
    // TRANSPOSED partial: column-contiguous for k_fin1's coalesced reduce
    ekspartT[(size_t)lane * 2048 + blockIdx.x] =
        (eks_s[0][lane] + eks_s[1][lane]) + (eks_s[2][lane] + eks_s[3][lane]);
    if (lane == 0)
      mkpart[blockIdx.x] =
          fmaxf(fmaxf(mk_s[0], mk_s[1]), fmaxf(mk_s[2], mk_s[3]));
  }
}

// ---------------------------------------------------------------------------
// k_kv: v = relu(Weff@xt + g2[n]); partial E_kv/VsumT per block (no atomics)
// grid 1024: b = blk&3, kb = blk>>2 (256 partials per batch)
// ---------------------------------------------------------------------------
__global__ __launch_bounds__(256) void k_kv(
    const float* __restrict__ xp, const float* __restrict__ Weff,
    const float* __restrict__ g2_in, const float* __restrict__ ek_in,
    float* __restrict__ part, float* __restrict__ vpartT)
{
  const int lane = threadIdx.x & 63;
  const int wv = threadIdx.x >> 6;
  const int b = blockIdx.x & 3;
  const int kb = blockIdx.x >> 2;
  const int wInB = kb * 4 + wv;
  const int strideB = 1024;

  float wrow[12];
  #pragma unroll
  for (int t = 0; t < 12; ++t) wrow[t] = Weff[lane * 12 + t];

  float acc[64];
  #pragma unroll
  for (int r = 0; r < 64; ++r) acc[r] = 0.f;
  float vs = 0.f;

  for (int n = wInB; n < NN; n += strideB) {
    const int nu = __builtin_amdgcn_readfirstlane(n);
    const float4* xp4 = (const float4*)(xp + ((size_t)b * NN + nu) * 12);
    float4 c0 = xp4[0], c1 = xp4[1], c2 = xp4[2];
    float v0 = fmaf(c0.x, wrow[0], g2_in[(size_t)nu * 64 + lane]);
    float v1 = c0.y * wrow[1], v2 = c0.z * wrow[2], v3 = c0.w * wrow[3];
    v0 = fmaf(c1.x, wrow[4], v0); v1 = fmaf(c1.y, wrow[5], v1);
    v2 = fmaf(c1.z, wrow[6], v2); v3 = fmaf(c1.w, wrow[7], v3);
    v0 = fmaf(c2.x, wrow[8], v0); v1 = fmaf(c2.y, wrow[9], v1);
    v2 = fmaf(c2.z, wrow[10], v2); v3 = fmaf(c2.w, wrow[11], v3);
    const float v = fmaxf((v0 + v1) + (v2 + v3), 0.f);
    const float4* ekp = (const float4*)(ek_in + (size_t)nu * 64);
    #pragma unroll
    for (int k = 0; k < 16; ++k) {
      float4 e = ekp[k];
      acc[4*k]   = fmaf(e.x, v, acc[4*k]);
      acc[4*k+1] = fmaf(e.y, v, acc[4*k+1]);
      acc[4*k+2] = fmaf(e.z, v, acc[4*k+2]);
      acc[4*k+3] = fmaf(e.w, v, acc[4*k+3]);
    }
    vs += v;
  }

  __shared__ float pkv[64][65];
  __shared__ float pvs[64];
  if (wv == 0) {
    #pragma unroll
    for (int r = 0; r < 64; ++r) pkv[r][lane] = acc[r];
    pvs[lane] = vs;
  }
  __syncthreads();
  for (int w = 1; w < 4; ++w) {
    if (wv == w) {
      #pragma unroll
      for (int r = 0; r < 64; ++r) pkv[r][lane] += acc[r];
      pvs[lane] += vs;
    }
    __syncthreads();
  }
  const size_t base = (size_t)(b * 256 + kb) * 4096;
  for (int i = threadIdx.x; i < 4096; i += 256)
    part[base + i] = pkv[i >> 6][i & 63];
  if (threadIdx.x < 64)   // TRANSPOSED: vpartT[(b,c)][kb]
    vpartT[((size_t)b * 64 + threadIdx.x) * 256 + kb] = pvs[threadIdx.x];
}

// ---------------------------------------------------------------------------
// k_fin1 (grid 81): parallel coalesced reductions.
//  blocks 0-63 : Vsum[b][c]  — wave per (b,c): 1 float4/lane + wave_sum
//  blocks 64-79: ekscol[c]   — wave per c: 8 float4/lane + wave_sum
//  block  80   : sc = exp(-max(mkpart))
// ---------------------------------------------------------------------------
__global__ __launch_bounds__(256) void k_fin1(
    const float* __restrict__ vpartT, const float* __restrict__ ekspartT,
    const float* __restrict__ mkpart,
    float* __restrict__ Vsum, float* __restrict__ ekscol,
    float* __restrict__ sc_out)
{
  const int lane = threadIdx.x & 63;
  const int wv = threadIdx.x >> 6;
  if (blockIdx.x < 64) {
    const int pair = blockIdx.x * 4 + wv;       // (b*64+c), 256 total
    const float4 v = ((const float4*)(vpartT + (size_t)pair * 256))[lane];
    const float s = wave_sum((v.x + v.y) + (v.z + v.w));
    if (lane == 0) Vsum[pair] = s;
  } else if (blockIdx.x < 80) {
    const int c = (blockIdx.x - 64) * 4 + wv;   // 64 total
    const float4* p = (const float4*)(ekspartT + (size_t)c * 2048);
    float s0 = 0.f, s1 = 0.f, s2 = 0.f, s3 = 0.f;
    #pragma unroll
    for (int k = 0; k < 8; ++k) {
      const float4 v = p[k * 64 + lane];
      s0 += v.x; s1 += v.y; s2 += v.z; s3 += v.w;
    }
    const float s = wave_sum((s0 + s1) + (s2 + s3));
    if (lane == 0) ekscol[c] = s;
  } else {
    const float4* p = (const float4*)mkpart;    // 512 float4
    const float4 a = p[threadIdx.x], b = p[threadIdx.x + 256];
    float m = fmaxf(fmaxf(fmaxf(a.x, a.y), fmaxf(a.z, a.w)),
                    fmaxf(fmaxf(b.x, b.y), fmaxf(b.z, b.w)));
    m = wave_max(m);
    __shared__ float ms[4];
    if (lane == 0) ms[wv] = m;
    __syncthreads();
    if (threadIdx.x == 0) {
      const float M = fmaxf(fmaxf(ms[0], ms[1]), fmaxf(ms[2], ms[3]));
      *sc_out = __expf(-M);
    }
  }
}

// ---------------------------------------------------------------------------
// k_fin2 (1 block): ks5frag = zeros; col-0 gets packed ksF in B-frag layout.
// ---------------------------------------------------------------------------
__global__ __launch_bounds__(256) void k_fin2(
    const float* __restrict__ ekscol, const float* __restrict__ sc_in,
    unsigned* __restrict__ ks5frag)
{
  const int t = threadIdx.x;
  #pragma unroll
  for (int q = 0; q < 4; ++q) ks5frag[t * 4 + q] = 0u;
  __syncthreads();
  if (t < 64) {
    const float ksv = fmaf(*sc_in, ekscol[t], EPSP * (float)NN);
    const int r = t;  // B-frag: lane=((r>>3)&3)*16 (col 0), j=r&7, ks=r>>5
    ks5frag[(r >> 5) * 512 + ((r >> 3) & 3) * 128 + (r & 7)] = packhl(ksv);
  }
}

// ---------------------------------------------------------------------------
// k_red: kv = sc*sum_kb part + eps*Vsum, written directly in MFMA B-frag
// layout, packed hi|lo. grid 512 x 256.
// ---------------------------------------------------------------------------
__global__ __launch_bounds__(256) void k_red(
    const float* __restrict__ part, const float* __restrict__ Vsum,
    const float* __restrict__ sc_in, unsigned* __restrict__ kvfrag)
{
  const int t = threadIdx.x;
  const int col0 = blockIdx.x * 32;
  const int c32 = t & 31, grp = t >> 5;          // 8 groups
  const int gid = col0 + c32;
  const int b = gid >> 12, idx = gid & 4095;
  float s = 0.f;
  for (int kb = grp; kb < 256; kb += 8)
    s += part[(size_t)(b * 256 + kb) * 4096 + idx];
  __shared__ float ls[8][33];
  ls[grp][c32] = s;
  __syncthreads();
  if (grp == 0) {
    float tot = 0.f;
    #pragma unroll
    for (int g = 0; g < 8; ++g) tot += ls[g][c32];
    const int r = idx >> 6, c = idx & 63;
    const float val = fmaf(*sc_in, tot, EPSP * Vsum[b * 64 + c]);
    // B-frag: tile ct=c>>4, ks=r>>5, lane=((r>>3)&3)*16+(c&15), j=r&7
    const int fi = (((b * 4 + (c >> 4)) * 2 + (r >> 5)) * 64 +
                    ((r >> 3) & 3) * 16 + (c & 15)) * 8 + (r & 7);
    kvfrag[fi] = packhl(val);
  }
}

// ---------------------------------------------------------------------------
// k_out: one wave per (batch, 64-node chunk). num+den via MFMA 16x16x32 bf16
// hi/lo (3 terms). D-layout -> LDS [64][65]+den[64] -> lane=node epilogue.
// ---------------------------------------------------------------------------
__global__ __launch_bounds__(64) void k_out(
    const float* __restrict__ xp, const float* __restrict__ node_emb,
    const float* __restrict__ w_input, const float* __restrict__ b_input,
    const unsigned* __restrict__ qphl, const unsigned* __restrict__ kvfrag,
    const unsigned* __restrict__ ks5frag,
    const float* __restrict__ ln_g, const float* __restrict__ ln_b,
    const float* __restrict__ w_reg, const float* __restrict__ b_reg,
    float* __restrict__ out)
{
  __shared__ float hb[64 * 65 + 64];
  const int lane = threadIdx.x;
  const int bu = __builtin_amdgcn_readfirstlane(blockIdx.x & 3);
  const int n0 = (blockIdx.x >> 2) * 64;
  const int arow = lane & 15, akg = lane >> 4;

  f32x4 acc[4][4];
  f32x4 acc5[4];
  #pragma unroll
  for (int nt = 0; nt < 4; ++nt) {
    #pragma unroll
    for (int ct = 0; ct < 4; ++ct) acc[nt][ct] = (f32x4)0.f;
    acc5[nt] = (f32x4)0.f;
  }

  #pragma unroll
  for (int ks = 0; ks < 2; ++ks) {
    bf16x8 Ah[4], Al[4];
    #pragma unroll
    for (int nt = 0; nt < 4; ++nt) {
      const uint4* ap = (const uint4*)(qphl +
          (size_t)(n0 + nt * 16 + arow) * 64 + ks * 32 + akg * 8);
      unpack8(ap[0], ap[1], Ah[nt], Al[nt]);
    }
    #pragma unroll
    for (int ct = 0; ct < 4; ++ct) {
      const uint4* bp = (const uint4*)(kvfrag +
          ((size_t)((bu * 4 + ct) * 2 + ks) * 64 + lane) * 8);
      bf16x8 Bh, Bl;
      unpack8(bp[0], bp[1], Bh, Bl);
      #pragma unroll
      for (int nt = 0; nt < 4; ++nt) {
        acc[nt][ct] = MFMA16(Ah[nt], Bh, acc[nt][ct], 0, 0, 0);
        acc[nt][ct] = MFMA16(Ah[nt], Bl, acc[nt][ct], 0, 0, 0);
        acc[nt][ct] = MFMA16(Al[nt], Bh, acc[nt][ct], 0, 0, 0);
      }
    }
    {
      const uint4* kp = (const uint4*)(ks5frag + ((size_t)(ks * 64 + lane)) * 8);
      bf16x8 Kh, Kl;
      unpack8(kp[0], kp[1], Kh, Kl);
      #pragma unroll
      for (int nt = 0; nt < 4; ++nt) {
        acc5[nt] = MFMA16(Ah[nt], Kh, acc5[nt], 0, 0, 0);
        acc5[nt] = MFMA16(Ah[nt], Kl, acc5[nt], 0, 0, 0);
        acc5[nt] = MFMA16(Al[nt], Kh, acc5[nt], 0, 0, 0);
      }
    }
  }

  #pragma unroll
  for (int nt = 0; nt < 4; ++nt)
    #pragma unroll
    for (int ct = 0; ct < 4; ++ct)
      #pragma unroll
      for (int reg = 0; reg < 4; ++reg)
        hb[(nt * 16 + akg * 4 + reg) * 65 + ct * 16 + arow] = acc[nt][ct][reg];
  if (arow == 0) {
    #pragma unroll
    for (int nt = 0; nt < 4; ++nt)
      #pragma unroll
      for (int reg = 0; reg < 4; ++reg)
        hb[4160 + nt * 16 + akg * 4 + reg] = acc5[nt][reg];
  }
  __syncthreads();

  // ---- per-lane epilogue: lane = node ----
  const int n = n0 + lane;
  const bool act = (n < NN);
  const int nld = act ? n : (NN - 1);
  const float den = hb[4160 + lane];
  const float rden = 1.f / den;

  float o_[12];
  #pragma unroll
  for (int o = 0; o < 12; ++o) o_[o] = b_reg[o];
  float h[64];

  {
    const float4* xp4 = (const float4*)(xp + ((size_t)bu * NN + nld) * 12);
    const float4 X0 = xp4[0], X1 = xp4[1], X2 = xp4[2];
    #pragma unroll
    for (int c = 0; c < 32; ++c) {
      float a = fmaf(X0.x, w_input[c*12+0], b_input[c]);
      a = fmaf(X0.y, w_input[c*12+1],  a);
      a = fmaf(X0.z, w_input[c*12+2],  a);
      a = fmaf(X0.w, w_input[c*12+3],  a);
      a = fmaf(X1.x, w_input[c*12+4],  a);
      a = fmaf(X1.y, w_input[c*12+5],  a);
      a = fmaf(X1.z, w_input[c*12+6],  a);
      a = fmaf(X1.w, w_input[c*12+7],  a);
      a = fmaf(X2.x, w_input[c*12+8],  a);
      a = fmaf(X2.y, w_input[c*12+9],  a);
      a = fmaf(X2.z, w_input[c*12+10], a);
      a = fmaf(X2.w, w_input[c*12+11], a);
      const float rx = fmaxf(a, 0.f);
      #pragma unroll
      for (int o = 0; o < 12; ++o) o_[o] = fmaf(rx, w_reg[o*128 + c], o_[o]);
      h[c] = fmaf(hb[lane * 65 + c], rden, a);
    }
    const float4* ne4 = (const float4*)(node_emb + (size_t)nld * 32);
    #pragma unroll
    for (int k = 0; k < 8; ++k) {
      const float4 nv = ne4[k];
      const float e[4] = {nv.x, nv.y, nv.z, nv.w};
      #pragma unroll
      for (int jj = 0; jj < 4; ++jj) {
        const int c = 32 + 4*k + jj;
        const float rx = fmaxf(e[jj], 0.f);
        #pragma unroll
        for (int o = 0; o < 12; ++o) o_[o] = fmaf(rx, w_reg[o*128 + c], o_[o]);
        h[c] = fmaf(hb[lane * 65 + c], rden, e[jj]);
      }
    }
  }

  float t0 = 0.f, t1 = 0.f, t2 = 0.f, t3 = 0.f;
  #pragma unroll
  for (int c = 0; c < 64; c += 4) {
    t0 += h[c]; t1 += h[c+1]; t2 += h[c+2]; t3 += h[c+3];
  }
  const float mean = ((t0 + t1) + (t2 + t3)) * 0.015625f;
  t0 = t1 = t2 = t3 = 0.f;
  #pragma unroll
  for (int c = 0; c < 64; c += 4) {
    const float d0 = h[c] - mean, d1 = h[c+1] - mean;
    const float d2 = h[c+2] - mean, d3 = h[c+3] - mean;
    t0 = fmaf(d0, d0, t0); t1 = fmaf(d1, d1, t1);
    t2 = fmaf(d2, d2, t2); t3 = fmaf(d3, d3, t3);
  }
  const float rstd = rsqrtf(((t0 + t1) + (t2 + t3)) * 0.015625f + 1e-5f);
  #pragma unroll
  for (int c = 0; c < 64; ++c)
    h[c] = fmaxf(fmaf((h[c] - mean) * rstd, ln_g[c], ln_b[c]), 0.f);

  #pragma unroll 2
  for (int o = 0; o < 12; ++o) {
    float a0 = o_[o], a1 = 0.f, a2 = 0.f, a3 = 0.f;
    #pragma unroll
    for (int c = 0; c < 64; c += 4) {
      a0 = fmaf(h[c],   w_reg[o*128 + 64 + c], a0);
      a1 = fmaf(h[c+1], w_reg[o*128 + 65 + c], a1);
      a2 = fmaf(h[c+2], w_reg[o*128 + 66 + c], a2);
      a3 = fmaf(h[c+3], w_reg[o*128 + 67 + c], a3);
    }
    o_[o] = (a0 + a1) + (a2 + a3);
  }

  if (act) {
    float* ob = out + ((size_t)bu * NN + n) * 12;
    float4 s0, s1, s2;
    s0.x = o_[0];  s0.y = o_[1];  s0.z = o_[2];  s0.w = o_[3];
    s1.x = o_[4];  s1.y = o_[5];  s1.z = o_[6];  s1.w = o_[7];
    s2.x = o_[8];  s2.y = o_[9];  s2.z = o_[10]; s2.w = o_[11];
    ((float4*)ob)[0] = s0; ((float4*)ob)[1] = s1; ((float4*)ob)[2] = s2;
  }
}

// ---------------------------------------------------------------------------
extern "C" void kernel_launch(void* const* d_in, const int* in_sizes, int n_in,
                              void* d_out, int out_size, void* d_ws, size_t ws_size,
                              hipStream_t stream) {
  (void)in_sizes; (void)n_in; (void)out_size; (void)ws_size;
  const float* x       = (const float*)d_in[0];
  const float* node    = (const float*)d_in[1];
  const float* w_input = (const float*)d_in[4];
  const float* b_input = (const float*)d_in[5];
  const float* w1      = (const float*)d_in[6];
  const float* b1      = (const float*)d_in[7];
  const float* w2      = (const float*)d_in[8];
  const float* b2      = (const float*)d_in[9];
  const float* fc_w    = (const float*)d_in[14];
  const float* fc_b    = (const float*)d_in[15];
  const float* ln_g    = (const float*)d_in[18];
  const float* ln_b    = (const float*)d_in[19];
  const float* w_reg   = (const float*)d_in[22];
  const float* b_reg   = (const float*)d_in[23];
  const float* rm1     = (const float*)d_in[24];

  // workspace layout (float offsets):
  float* ws         = (float*)d_ws;
  float* sc         = ws;                       // 1 (pad 16)
  float* ekscol     = ws + 16;                  // 64 (ends 80)
  float* Weff       = ws + 128;                 // 768
  float* beff       = ws + 896;                 // 64
  unsigned* kvfrag  = (unsigned*)(ws + 960);    // 16384
  unsigned* ks5frag = (unsigned*)(ws + 17344);  // 1024
  float* Vsum       = ws + 18368;               // 256
  float* mkpart     = ws + 18624;               // 2048
  float* ekspartT   = ws + 20672;               // 64*2048 = 131072
  unsigned* qphl    = (unsigned*)(ws + 151744); // 3,200,000
  float* ek         = ws + 3351744;             // 3,200,000
  float* g2         = ws + 6551744;             // 3,200,000
  float* xp         = ws + 9751744;             // 2,400,000
  float* part       = ws + 12151744;            // 1024*4096 = 4,194,304
  float* vpartT     = ws + 16346048;            // 4*64*256 = 65,536
  // total 16,411,584 floats = 65.6 MB

  k_weff<<<1, 64, 0, stream>>>(fc_w, w_input, b_input, fc_b, Weff, beff);
  k_xpack<<<2344, 256, 0, stream>>>(x, xp);
  k_node<<<2048, 256, 0, stream>>>(node, w1, b1, w2, b2, rm1, fc_w, beff,
                                   qphl, ek, g2, ekspartT, mkpart);
  k_kv<<<1024, 256, 0, stream>>>(xp, Weff, g2, ek, part, vpartT);
  k_fin1<<<81, 256, 0, stream>>>(vpartT, ekspartT, mkpart, Vsum, ekscol, sc);
  k_fin2<<<1, 256, 0, stream>>>(ekscol, sc, ks5frag);
  k_red<<<512, 256, 0, stream>>>(part, Vsum, sc, kvfrag);
  k_out<<<3128, 64, 0, stream>>>(xp, node, w_input, b_input, qphl, kvfrag,
                                 ks5frag, ln_g, ln_b, w_reg, b_reg,
                                 (float*)d_out);
}